// Round 6
// baseline (783.078 us; speedup 1.0000x reference)
//
#include <hip/hip_runtime.h>
#include <math.h>

#define THREADS 256

// ---------------- problem constants (fixed by reference setup) ----------------
constexpr int NLEV  = 5;
constexpr int NB    = 16;     // batch
constexpr int NC    = 80;     // classes (label = c+1)
constexpr int TOPN  = 300;
constexpr int KC    = NLEV * TOPN;   // 1500 candidates per image
constexpr int KROWS = 1536;          // padded rows for NMS bitmask
constexpr int WORDS = 24;            // 1536 / 64
constexpr int NTRI  = WORDS * (WORDS + 1) / 2;   // 300 lower-triangle tiles
constexpr int POSTN = 100;
constexpr int CAP   = 4096;          // per-(b,level) candidate pool
constexpr int NBINS = 2048;          // score-histogram bins over [0.25, 1.0)
constexpr int NPAIR = NLEV * NB;     // 80

constexpr int HW0 = 12800, HW1 = 3200, HW2 = 800, HW3 = 208, HW4 = 56;
constexpr int CH0 = 63, CH1 = 16, CH2 = 4, CH3 = 2, CH4 = 1;  // 16384-elem chunks per (b,level)
constexpr int CHUNKS = CH0 + CH1 + CH2 + CH3 + CH4;           // 86

// group-max skip list: 256-element groups, layout [li][b][g] (u16)
constexpr int GPL0 = 4000, GPL1 = 1000, GPL2 = 250, GPL3 = 65, GPL4 = 18;
constexpr int GMXB0 = 0;
constexpr int GMXB1 = GMXB0 + NB * GPL0;
constexpr int GMXB2 = GMXB1 + NB * GPL1;
constexpr int GMXB3 = GMXB2 + NB * GPL2;
constexpr int GMXB4 = GMXB3 + NB * GPL3;
constexpr int GMXN  = GMXB4 + NB * GPL4;

constexpr int BPP = 16;          // collect blocks per pid (max slice 4000/16=250 < THREADS)

// persistent-kernel geometry: __launch_bounds__(256,4) guarantees 4 blocks/CU
// (VGPR<=128 enforced by compiler, LDS 32.8KB<=40KB) -> 4*256CU = 1024 blocks ALL
// co-resident at dispatch => software grid barrier cannot deadlock.
constexpr int NBLK   = 1024;
constexpr int LEAVES = 64;
constexpr int BPL    = NBLK / LEAVES;   // 16 arrivals per leaf per phase

// histogram floor per level: big levels (top-300 of >=64K elems) always threshold
// far above s=0.5 (bin 1024) -> skip ~90% of LDS atomics. Small levels keep floor 1.
constexpr int HF_BIG = 1024, HF_SMALL = 1;

// ---------------- workspace layout ----------------
constexpr size_t align256(size_t x) { return (x + 255) & ~(size_t)255; }
constexpr size_t OFF_HIST = 0;
constexpr size_t OFF_CNT  = OFF_HIST + (size_t)NPAIR * NBINS * 4;
constexpr size_t OFF_BAR  = OFF_CNT + (size_t)NPAIR * 4;     // barrier: 64 padded leaves + root + release
constexpr size_t BARWORDS = 1056;                            // 64*16 + pad; root@1024, rel@1040
constexpr size_t OFF_CAND = align256(OFF_BAR + BARWORDS * 4);
constexpr size_t OFF_CBOX = align256(OFF_CAND + (size_t)NPAIR * CAP * 8);
constexpr size_t OFF_CSC  = align256(OFF_CBOX + (size_t)NB * KC * 4 * 4);
constexpr size_t OFF_CLB  = align256(OFF_CSC  + (size_t)NB * KC * 4);
constexpr size_t OFF_SSC  = align256(OFF_CLB  + (size_t)NB * KC * 4);
constexpr size_t OFF_SLB  = align256(OFF_SSC  + (size_t)NB * KC * 4);
constexpr size_t OFF_SBOX = align256(OFF_SLB  + (size_t)NB * KC * 4);
constexpr size_t OFF_OBOX = align256(OFF_SBOX + (size_t)NB * KC * 4 * 4);
constexpr size_t OFF_M    = align256(OFF_OBOX + (size_t)NB * KC * 4 * 4);
constexpr size_t OFF_GMX  = align256(OFF_M + (size_t)NB * KROWS * WORDS * 8);
// total ~9.7 MB

struct Cand { float s; int i; };

// ---------------- helpers ----------------
__device__ __forceinline__ float sigm(float x) { return 1.0f / (1.0f + expf(-x)); }

__device__ __forceinline__ float sigf(float x) {
#if __has_builtin(__builtin_amdgcn_exp2f) && __has_builtin(__builtin_amdgcn_rcpf)
    float e = __builtin_amdgcn_exp2f(__fmul_rn(x, -1.44269504088896340736f));
    return __builtin_amdgcn_rcpf(__fadd_rn(1.0f, e));
#else
    return 1.0f / (1.0f + __expf(-x));
#endif
}

// monotone key over score in (0,1): 2048 bins over [0.25,1.0), everything below -> bin 0
__device__ __forceinline__ unsigned scoreKey(float s) {
    unsigned b = __float_as_uint(s);
    unsigned k = (b < 0x3E800000u) ? 0u : ((b - 0x3E800000u) >> 13);
    return (k > 2047u) ? 2047u : k;
}

__device__ __forceinline__ unsigned long long readlane64(unsigned long long v, int l) {
    unsigned lo = (unsigned)__builtin_amdgcn_readlane((int)(unsigned)(v & 0xffffffffull), l);
    unsigned hi = (unsigned)__builtin_amdgcn_readlane((int)(unsigned)(v >> 32), l);
    return ((unsigned long long)hi << 32) | lo;
}

__device__ void bitonicShared(float* ss, int* si, int N) {
    for (int k = 2; k <= N; k <<= 1) {
        for (int j = k >> 1; j > 0; j >>= 1) {
            __syncthreads();
            for (int i = threadIdx.x; i < N; i += blockDim.x) {
                int ixj = i ^ j;
                if (ixj > i) {
                    float s1 = ss[i], s2 = ss[ixj];
                    int a1 = si[i], a2 = si[ixj];
                    bool bef = (s1 > s2) || (s1 == s2 && a1 < a2);   // desc, idx asc
                    bool up = ((i & k) == 0);
                    if (up ? !bef : bef) { ss[i] = s2; ss[ixj] = s1; si[i] = a2; si[ixj] = a1; }
                }
            }
        }
    }
    __syncthreads();
}

// software grid barrier (Guideline-16: device-scope atomics + fences; all blocks
// co-resident by construction). Hierarchical: 64 padded leaf counters (16 arrivals
// each) -> root -> release flag; counters are monotone across phases (no reset).
__device__ __forceinline__ void gridBar(unsigned* bar, int phase) {
    __syncthreads();
    if (threadIdx.x == 0) {
        __threadfence();   // device-scope release of this block's prior writes (L2 writeback)
        int leaf = (int)(blockIdx.x & (LEAVES - 1));
        unsigned v = __hip_atomic_fetch_add(&bar[leaf * 16], 1u,
                        __ATOMIC_ACQ_REL, __HIP_MEMORY_SCOPE_AGENT);
        if (v == (unsigned)(BPL * (phase + 1) - 1)) {
            unsigned r = __hip_atomic_fetch_add(&bar[1024], 1u,
                            __ATOMIC_ACQ_REL, __HIP_MEMORY_SCOPE_AGENT);
            if (r == (unsigned)(LEAVES * (phase + 1) - 1))
                __hip_atomic_store(&bar[1040], (unsigned)(phase + 1),
                                   __ATOMIC_RELEASE, __HIP_MEMORY_SCOPE_AGENT);
        }
        while (__hip_atomic_load(&bar[1040], __ATOMIC_ACQUIRE, __HIP_MEMORY_SCOPE_AGENT)
               < (unsigned)(phase + 1))
            __builtin_amdgcn_s_sleep(8);
    }
    __syncthreads();
}

// ---------------- phase bodies (identical math to round-5 kernels) ----------------
template<int HW, int GPL, int GMXB, int HF>
__device__ __forceinline__ void histChunkV(int chunkLocal, int b,
        const float* __restrict__ cls, const float* __restrict__ ctr,
        unsigned short* __restrict__ gmx, unsigned* __restrict__ h) {
    constexpr int NE = HW * NC;
    const float* cp = cls + (size_t)b * NE;
    const float* tb = ctr + (size_t)b * HW;
    unsigned short* gp = gmx + GMXB + (size_t)b * GPL;
    int w = threadIdx.x >> 6, lane = threadIdx.x & 63;
    int half = lane >> 5, hlane = lane & 31;
    for (int bi = w; bi < 32; bi += 4) {
        int ebase = (chunkLocal * 32 + bi) * 512;
        if (ebase >= NE) break;
        int e = ebase + lane * 8;
        int kmax = 0;
        if (e < NE) {   // NE%8==0 -> e<NE implies e+7<NE
            int c = e / HW; int hwb = e - c * HW;
            float4 xa = *(const float4*)(cp + e);
            float4 xb = *(const float4*)(cp + e + 4);
            float4 ta = *(const float4*)(tb + hwb);
            float4 tc = *(const float4*)(tb + hwb + 4);
            float xs[8] = {xa.x, xa.y, xa.z, xa.w, xb.x, xb.y, xb.z, xb.w};
            float ts[8] = {ta.x, ta.y, ta.z, ta.w, tc.x, tc.y, tc.z, tc.w};
            #pragma unroll
            for (int q = 0; q < 8; ++q) {
                float scls = sigf(xs[q]);                // FAST sigmoid (approx key)
                float s = __fmul_rn(scls, sigf(ts[q]));  // FAST sigmoid(ctr) inline
                unsigned key = scoreKey(s);
                if (key >= (unsigned)HF) atomicAdd(&h[key], 1u);
                kmax = max(kmax, (int)key);
            }
        }
        #pragma unroll
        for (int sh = 1; sh < 32; sh <<= 1) kmax = max(kmax, __shfl_xor(kmax, sh, 64));
        int g = (ebase >> 8) + half;
        if (hlane == 0 && g * 256 < NE) gp[g] = (unsigned short)kmax;
    }
}

constexpr int LBUF = 1024;
constexpr int GB = 8;

template<int HW>
__device__ __forceinline__ void procList(int b, int pid, unsigned Tv, unsigned n,
        const unsigned short* __restrict__ glist,
        const float* __restrict__ cls, const float* __restrict__ ctr,
        Cand* __restrict__ cd, unsigned* __restrict__ cnt,
        Cand* __restrict__ lbuf, unsigned* __restrict__ lcnt) {
    constexpr int NE = HW * NC;
    const float* cp = cls + (size_t)b * NE;
    const float* tb = ctr + (size_t)b * HW;
    for (unsigned base = 0; base < n; base += GB) {
        float xv[GB], rv[GB];
        int ev[GB];
        bool okv[GB];
        #pragma unroll
        for (int q = 0; q < GB; ++q) {
            unsigned gi = base + q;
            int g = glist[(gi < n) ? gi : (n - 1)];   // n >= 1 guaranteed by caller
            int e = g * 256 + (int)threadIdx.x;
            bool ok = (gi < n) && (e < NE);
            e = ok ? e : 0;
            int c = e / HW; int hw = e - c * HW;
            xv[q] = cp[e];
            rv[q] = tb[hw];
            ev[q] = e;
            okv[q] = ok;
        }
        __builtin_amdgcn_sched_barrier(0);   // keep the 2*GB loads batched above the uses
        #pragma unroll
        for (int q = 0; q < GB; ++q) {
            float scls = sigm(xv[q]);                    // EXACT sigmoid(cls)
            float s = __fmul_rn(scls, sigm(rv[q]));      // EXACT sigmoid(ctr)
            unsigned key = scoreKey(s);
            bool take = okv[q] && (Tv ? (key >= Tv) : (scls > 0.05f));
            if (take) {
                int e = ev[q];
                int c = e / HW; int hw = e - c * HW;
                unsigned slot = atomicAdd(lcnt, 1u);
                if (slot < (unsigned)LBUF) { lbuf[slot].s = s; lbuf[slot].i = hw * NC + c; }
                else {
                    unsigned gs = atomicAdd(&cnt[pid], 1u);   // rare fallback
                    if (gs < (unsigned)CAP) { cd[gs].s = s; cd[gs].i = hw * NC + c; }
                }
            }
        }
    }
}

// ---------------- K0: zero hist+cnt+barrier state ----------------
__global__ __launch_bounds__(THREADS) void k_zero(unsigned* __restrict__ zp, int zn) {
    int i = blockIdx.x * THREADS + threadIdx.x;
    if (i < zn) zp[i] = 0;
}

// ---------------- K1: persistent mega-kernel — all six phases, 5 grid barriers -------
__global__ __launch_bounds__(THREADS, 4) void k_mega(
        const float* l0, const float* l1, const float* l2, const float* l3, const float* l4,
        const float* c0, const float* c1, const float* c2, const float* c3, const float* c4,
        const float* b0, const float* b1, const float* b2, const float* b3, const float* b4,
        const float* t0, const float* t1, const float* t2, const float* t3, const float* t4,
        char* __restrict__ ws, float* __restrict__ out) {
    __shared__ __align__(16) char smem[32768];
    __shared__ unsigned shTv, lcnt, gbase, gcnt;
    __shared__ int tstar;

    unsigned* ghist = (unsigned*)(ws + OFF_HIST);
    unsigned* cnt   = (unsigned*)(ws + OFF_CNT);
    unsigned* bar   = (unsigned*)(ws + OFF_BAR);
    Cand* cand      = (Cand*)(ws + OFF_CAND);
    float* cbox     = (float*)(ws + OFF_CBOX);
    float* csc      = (float*)(ws + OFF_CSC);
    int*   clb      = (int*)(ws + OFF_CLB);
    float* ssc      = (float*)(ws + OFF_SSC);
    int*   slb      = (int*)(ws + OFF_SLB);
    float* sbox     = (float*)(ws + OFF_SBOX);
    float* obox     = (float*)(ws + OFF_OBOX);
    unsigned long long* MT = (unsigned long long*)(ws + OFF_M);
    unsigned short* gmx = (unsigned short*)(ws + OFF_GMX);

    const int tid = (int)threadIdx.x;
    const int bid = (int)blockIdx.x;

    // ================= phase 0: histogram + group-max =================
    {
        unsigned* h = (unsigned*)smem;
        for (int item = bid; item < CHUNKS * NB; item += NBLK) {
            __syncthreads();
            for (int k = tid; k < NBINS; k += THREADS) h[k] = 0;
            __syncthreads();
            int cx = item % CHUNKS, b = item / CHUNKS;
            int li;
            if (cx < CH0)                 { histChunkV<HW0,GPL0,GMXB0,HF_BIG>(cx, b, c0, t0, gmx, h); li = 0; }
            else if (cx < CH0+CH1)        { histChunkV<HW1,GPL1,GMXB1,HF_BIG>(cx-CH0, b, c1, t1, gmx, h); li = 1; }
            else if (cx < CH0+CH1+CH2)    { histChunkV<HW2,GPL2,GMXB2,HF_BIG>(cx-CH0-CH1, b, c2, t2, gmx, h); li = 2; }
            else if (cx < CH0+CH1+CH2+CH3){ histChunkV<HW3,GPL3,GMXB3,HF_SMALL>(cx-CH0-CH1-CH2, b, c3, t3, gmx, h); li = 3; }
            else                          { histChunkV<HW4,GPL4,GMXB4,HF_SMALL>(cx-CH0-CH1-CH2-CH3, b, c4, t4, gmx, h); li = 4; }
            __syncthreads();
            unsigned* gp = ghist + (size_t)(li * NB + b) * NBINS;
            for (int k = tid; k < NBINS; k += THREADS) {
                unsigned v = h[k];
                if (v) atomicAdd(&gp[k], v);
            }
        }
    }
    gridBar(bar, 0);

    // ================= phase 1: threshold + slice-scan + compaction =================
    {
        unsigned* sfx = (unsigned*)smem;                          // 1 KB
        Cand* lbuf = (Cand*)(smem + 1024);                        // 8 KB
        unsigned short* glist = (unsigned short*)(smem + 9216);   // 512 B
        for (int item = bid; item < BPP * NPAIR; item += NBLK) {
            __syncthreads();
            if (tid == 0) { lcnt = 0; gcnt = 0; tstar = -1; }
            int pid = item % NPAIR;
            int bx  = item / NPAIR;
            int li = pid >> 4, b = pid & 15;
            // Tv: parallel suffix-scan over 256 8-bin segments
            const unsigned* h = ghist + (size_t)pid * NBINS;
            unsigned s = 0;
            #pragma unroll
            for (int k = 0; k < 8; ++k) s += h[tid * 8 + k];
            sfx[tid] = s;
            for (int d = 1; d < THREADS; d <<= 1) {
                __syncthreads();
                unsigned v = (tid + d < THREADS) ? sfx[tid + d] : 0u;
                __syncthreads();
                sfx[tid] += v;
            }
            __syncthreads();
            if (sfx[tid] >= (unsigned)TOPN && (tid == THREADS - 1 || sfx[tid + 1] < (unsigned)TOPN))
                tstar = tid;   // sfx non-increasing -> unique
            __syncthreads();
            if (tid == 0) {
                unsigned TA = 0;
                int t = tstar;
                if (t >= 0) {
                    unsigned acc = (t < THREADS - 1) ? sfx[t + 1] : 0u;
                    int lo = t * 8, bin = lo + 7;
                    for (; bin >= lo; --bin) { acc += h[bin]; if (acc >= (unsigned)TOPN) break; }
                    TA = (unsigned)max(bin, lo);
                }
                shTv = (TA >= 1) ? (TA - 1) : 0u;
            }
            __syncthreads();
            unsigned Tv = shTv;
            int GPL, GMXB;
            switch (li) {
                case 0: GPL = GPL0; GMXB = GMXB0; break;
                case 1: GPL = GPL1; GMXB = GMXB1; break;
                case 2: GPL = GPL2; GMXB = GMXB2; break;
                case 3: GPL = GPL3; GMXB = GMXB3; break;
                default: GPL = GPL4; GMXB = GMXB4; break;
            }
            const unsigned short* gp = gmx + GMXB + (size_t)b * GPL;
            int per = (GPL + BPP - 1) / BPP;
            int lo = bx * per;
            int hi = min(GPL, lo + per);
            {
                int g = lo + tid;
                bool ok = (g < hi);
                if (ok && Tv) ok = ((unsigned)gp[g] + 1u >= Tv);   // gmx is max APPROX key
                unsigned long long m = __ballot(ok);
                int nW = __popcll(m);
                if (nW) {
                    unsigned wb = 0;
                    if ((tid & 63) == 0) wb = atomicAdd(&gcnt, (unsigned)nW);   // LDS atomic
                    wb = (unsigned)__builtin_amdgcn_readfirstlane((int)wb);
                    if (ok) glist[wb + (unsigned)__popcll(m & ((1ull << (tid & 63)) - 1ull))] = (unsigned short)g;
                }
            }
            __syncthreads();
            unsigned n = gcnt;
            Cand* cd = cand + (size_t)pid * CAP;
            if (n) {
                switch (li) {
                    case 0: procList<HW0>(b, pid, Tv, n, glist, c0, t0, cd, cnt, lbuf, &lcnt); break;
                    case 1: procList<HW1>(b, pid, Tv, n, glist, c1, t1, cd, cnt, lbuf, &lcnt); break;
                    case 2: procList<HW2>(b, pid, Tv, n, glist, c2, t2, cd, cnt, lbuf, &lcnt); break;
                    case 3: procList<HW3>(b, pid, Tv, n, glist, c3, t3, cd, cnt, lbuf, &lcnt); break;
                    default: procList<HW4>(b, pid, Tv, n, glist, c4, t4, cd, cnt, lbuf, &lcnt); break;
                }
            }
            __syncthreads();
            unsigned nl = lcnt; if (nl > (unsigned)LBUF) nl = LBUF;
            if (tid == 0) gbase = nl ? atomicAdd(&cnt[pid], nl) : 0u;
            __syncthreads();
            for (unsigned i = tid; i < nl; i += THREADS) {
                unsigned sl = gbase + i;
                if (sl < (unsigned)CAP) cd[sl] = lbuf[i];
            }
        }
    }
    gridBar(bar, 1);

    // ================= phase 2: exact top-300 per (b,level) + decode =================
    {
        float* ss = (float*)smem;             // 16 KB
        int* si = (int*)(smem + 16384);       // 16 KB
        for (int pid = bid; pid < NPAIR; pid += NBLK) {
            int li = pid / NB, b = pid - li * NB;
            int n = (int)min(cnt[pid], (unsigned)CAP);
            const Cand* cd = cand + (size_t)pid * CAP;
            int N = 2; while (N < n) N <<= 1;
            for (int k = tid; k < N; k += THREADS) {
                if (k < n) { ss[k] = cd[k].s; si[k] = cd[k].i; }
                else       { ss[k] = -INFINITY; si[k] = 0x40000000 + k; }
            }
            __syncthreads();
            bitonicShared(ss, si, N);
            const float* locp; const float* boxp; int HW;
            switch (li) {
                case 0: locp = l0; boxp = b0; HW = HW0; break;
                case 1: locp = l1; boxp = b1; HW = HW1; break;
                case 2: locp = l2; boxp = b2; HW = HW2; break;
                case 3: locp = l3; boxp = b3; HW = HW3; break;
                default: locp = l4; boxp = b4; HW = HW4; break;
            }
            for (int j = tid; j < TOPN; j += THREADS) {
                int cidx = b * KC + li * TOPN + j;
                bool ok = (j < n);
                float s = ok ? ss[j] : -INFINITY;
                ok = ok && (s > 0.0f);
                if (ok) {
                    int idx = si[j];
                    int hw = idx / NC, c = idx - hw * NC;
                    float lx = locp[hw * 2 + 0], ly = locp[hw * 2 + 1];
                    const float* bp = boxp + (size_t)b * 4 * HW + hw;
                    float bl = bp[0], bt = bp[HW], br = bp[2 * HW], bb = bp[3 * HW];
                    float x1 = fminf(fmaxf(__fsub_rn(lx, bl), 0.0f), 1023.0f);
                    float y1 = fminf(fmaxf(__fsub_rn(ly, bt), 0.0f),  799.0f);
                    float x2 = fminf(fmaxf(__fadd_rn(lx, br), 0.0f), 1023.0f);
                    float y2 = fminf(fmaxf(__fadd_rn(ly, bb), 0.0f),  799.0f);
                    cbox[cidx * 4 + 0] = x1; cbox[cidx * 4 + 1] = y1;
                    cbox[cidx * 4 + 2] = x2; cbox[cidx * 4 + 3] = y2;
                    csc[cidx] = sqrtf(fmaxf(s, 1e-12f));
                    clb[cidx] = c + 1;
                } else {
                    cbox[cidx * 4 + 0] = 0.0f; cbox[cidx * 4 + 1] = 0.0f;
                    cbox[cidx * 4 + 2] = 0.0f; cbox[cidx * 4 + 3] = 0.0f;
                    csc[cidx] = -INFINITY;
                    clb[cidx] = 0;
                }
            }
            __syncthreads();
        }
    }
    gridBar(bar, 2);

    // ================= phase 3: 5-way merge by rank (stable argsort(-s)) =============
    {
        float* ms = (float*)smem;   // KC floats = 6 KB
        for (int item = bid; item < NLEV * NB; item += NBLK) {
            int li = item % NLEV, b = item / NLEV;
            for (int k = tid; k < KC; k += THREADS) ms[k] = csc[b * KC + k];
            __syncthreads();
            for (int j = tid; j < TOPN; j += THREADS) {
                int k = li * TOPN + j;
                float s = ms[k];
                int rank = j;
                #pragma unroll
                for (int l = 0; l < NLEV; ++l) {
                    if (l == li) continue;                 // wave-uniform branch
                    const float* seg = ms + l * TOPN;
                    int lo = 0, hi = TOPN;
                    if (l < li) {
                        while (lo < hi) { int m = (lo + hi) >> 1; if (seg[m] >= s) lo = m + 1; else hi = m; }
                    } else {
                        while (lo < hi) { int m = (lo + hi) >> 1; if (seg[m] >  s) lo = m + 1; else hi = m; }
                    }
                    rank += lo;
                }
                int src = b * KC + k, dst = b * KC + rank;
                int lab = clb[src];
                ssc[dst] = s; slb[dst] = lab;
                float off = __fmul_rn((float)lab, 1025.0f);   // offset = max(800,1024)+1
                float4 v = *(const float4*)&cbox[(size_t)src * 4];
                *(float4*)&sbox[(size_t)dst * 4] = v;
                float4 o;
                o.x = __fadd_rn(v.x, off); o.y = __fadd_rn(v.y, off);
                o.z = __fadd_rn(v.z, off); o.w = __fadd_rn(v.w, off);
                *(float4*)&obox[(size_t)dst * 4] = o;
            }
            __syncthreads();
        }
    }
    gridBar(bar, 3);

    // ================= phase 4: IoU suppression bitmask (wave-private, barrier-free) ==
    {
        float4* sj = (float4*)smem;             // [4][64] = 4 KB
        float*  aj = (float*)(smem + 4096);     // [4][64] = 1 KB
        int wid = tid >> 6, lane = tid & 63;
        float4* sjW = sj + wid * 64;
        float*  ajW = aj + wid * 64;
        for (int base = bid * 4; base < NTRI * NB; base += NBLK * 4) {
            int wit = base + wid;
            bool act = (wit < NTRI * NB);
            int t = act ? (wit % NTRI) : 0;
            int b = act ? (wit / NTRI) : 0;
            int tile = 0, rem = t;
            while (rem >= WORDS - tile) { rem -= WORDS - tile; ++tile; }
            int w = tile + rem;
            const float4* op = (const float4*)obox + (size_t)b * KC;
            int j0 = w * 64;
            int jl = j0 + lane;
            float4 vj = op[(jl < KC) ? jl : (KC - 1)];
            sjW[lane] = vj;
            ajW[lane] = __fmul_rn(__fsub_rn(vj.z, vj.x), __fsub_rn(vj.w, vj.y));
            int i = tile * 64 + lane;
            float4 bi = op[(i < KC) ? i : (KC - 1)];
            float ai = __fmul_rn(__fsub_rn(bi.z, bi.x), __fsub_rn(bi.w, bi.y));
            unsigned long long bits = 0;
            int jmax = min(64, KC - j0);
            for (int jj = 0; jj < jmax; ++jj) {
                float4 bj = sjW[jj];            // wave-private LDS; same-wave dep -> lgkmcnt
                float xx1 = fmaxf(bi.x, bj.x), yy1 = fmaxf(bi.y, bj.y);
                float xx2 = fminf(bi.z, bj.z), yy2 = fminf(bi.w, bj.w);
                float ww = fmaxf(__fsub_rn(xx2, xx1), 0.0f);
                float hh = fmaxf(__fsub_rn(yy2, yy1), 0.0f);
                float inter = __fmul_rn(ww, hh);
                float uni = __fsub_rn(__fadd_rn(ai, ajW[jj]), inter);
                float iou = __fdiv_rn(inter, fmaxf(uni, 1e-9f));
                bool kp = ((j0 + jj) > i) && (iou > 0.6f);
                bits |= kp ? (1ull << jj) : 0ull;
            }
            if (i >= KC) bits = 0;
            if (act) MT[((size_t)b * WORDS + w) * KROWS + i] = bits;
        }
    }
    gridBar(bar, 4);

    // ================= phase 5: greedy NMS scan, early-exit at POSTN kept =============
    if (bid < NB && tid < 64) {
        int b = bid, lane = tid;
        for (int k = lane; k < POSTN * 5; k += 64) out[(size_t)b * POSTN * 5 + k] = 0.0f;
        for (int k = lane; k < POSTN; k += 64) {
            out[(size_t)NB * POSTN * 5 + b * POSTN + k] = 0.0f;                 // labels
            out[(size_t)NB * POSTN * 5 + NB * POSTN + b * POSTN + k] = 0.0f;    // valid
        }
        const float* sp = ssc + b * KC;
        unsigned long long validV = 0;
        for (int c = 0; c < WORDS; ++c) {
            int i = c * 64 + lane;
            bool f = (i < KC) && (sp[i] > 0.0f);
            unsigned long long m = __ballot(f);
            validV = (lane == c) ? m : validV;
        }
        unsigned long long mybit = 1ull << lane;
        unsigned long long keptV = 0;
        const unsigned long long* Mb = MT + (size_t)b * WORDS * KROWS;

        unsigned long long pv[WORDS];
        pv[0] = Mb[lane];

        int keptTotal = 0;
        for (int t = 0; t < WORDS; ++t) {
            int tn = (t + 1 < WORDS) ? (t + 1) : t;
            const unsigned long long* cp = Mb + (size_t)tn * KROWS + lane;
            unsigned long long nv[WORDS];
            #pragma unroll
            for (int c = 0; c < WORDS; ++c) {
                int cc = (c <= tn) ? c : 0;
                nv[c] = cp[(size_t)cc * 64];
            }
            __builtin_amdgcn_sched_barrier(0);    // loads stay above; compute below

            unsigned long long D = pv[t];
            unsigned long long acc = 0;
            #pragma unroll
            for (int c = 0; c < WORDS; ++c) {
                if (c < t) {
                    unsigned long long kc = readlane64(keptV, c);
                    if (kc & mybit) acc |= pv[c];
                }
            }
            #pragma unroll
            for (int s = 1; s < 64; s <<= 1) acc |= __shfl_xor(acc, s, 64);

            unsigned long long validT = readlane64(validV, t);
            unsigned long long rem = acc;
            unsigned long long sup = __ballot(D != 0ull) & validT;
            unsigned long long todoS = sup;
            while (todoS) {
                int r = __builtin_ctzll(todoS);
                todoS &= todoS - 1;
                if (!((rem >> r) & 1ull)) {
                    unsigned long long Dr = readlane64(D, r);
                    rem |= Dr;
                    todoS &= ~Dr;
                }
            }
            unsigned long long kept = validT & ~rem;
            keptV = (lane == t) ? kept : keptV;

            keptTotal += (int)__popcll(kept);      // kept is wave-uniform
            if (keptTotal >= POSTN) break;         // first POSTN kept fully determined

            #pragma unroll
            for (int c = 0; c < WORDS; ++c) pv[c] = nv[c];
        }

        int base = 0;
        for (int c = 0; c < WORDS && base < POSTN; ++c) {
            unsigned long long kw = readlane64(keptV, c);
            bool f = (kw & mybit) != 0ull;
            int rank = base + __popcll(kw & (mybit - 1ull));
            if (f && rank < POSTN) {
                int i = c * 64 + lane;
                int src = b * KC + i;
                float* o5 = out + ((size_t)b * POSTN + rank) * 5;
                o5[0] = sbox[src * 4 + 0]; o5[1] = sbox[src * 4 + 1];
                o5[2] = sbox[src * 4 + 2]; o5[3] = sbox[src * 4 + 3];
                o5[4] = ssc[src];
                out[(size_t)NB * POSTN * 5 + b * POSTN + rank] = (float)slb[src];
                out[(size_t)NB * POSTN * 5 + NB * POSTN + b * POSTN + rank] = 1.0f;
            }
            base += __popcll(kw);
        }
    }
}

// ---------------- launch (2 dispatches, was 7) ----------------
extern "C" void kernel_launch(void* const* d_in, const int* in_sizes, int n_in,
                              void* d_out, int out_size, void* d_ws, size_t ws_size,
                              hipStream_t stream) {
    const float *loc[5], *cls[5], *box[5], *ctr[5];
    for (int l = 0; l < 5; ++l) {
        loc[l] = (const float*)d_in[l * 4 + 0];
        cls[l] = (const float*)d_in[l * 4 + 1];
        box[l] = (const float*)d_in[l * 4 + 2];
        ctr[l] = (const float*)d_in[l * 4 + 3];
    }
    char* ws = (char*)d_ws;
    float* out = (float*)d_out;

    int zn = (int)(OFF_CAND / 4);   // hist + cnt + barrier state
    k_zero<<<(zn + THREADS - 1) / THREADS, THREADS, 0, stream>>>((unsigned*)ws, zn);
    k_mega<<<NBLK, THREADS, 0, stream>>>(
        loc[0], loc[1], loc[2], loc[3], loc[4],
        cls[0], cls[1], cls[2], cls[3], cls[4],
        box[0], box[1], box[2], box[3], box[4],
        ctr[0], ctr[1], ctr[2], ctr[3], ctr[4],
        ws, out);
}

// Round 7
// 470.738 us; speedup vs baseline: 1.6635x; 1.6635x over previous
//
#include <hip/hip_runtime.h>
#include <math.h>

#define THREADS 256

// ---------------- problem constants (fixed by reference setup) ----------------
constexpr int NLEV  = 5;
constexpr int NB    = 16;     // batch
constexpr int NC    = 80;     // classes (label = c+1)
constexpr int TOPN  = 300;
constexpr int KC    = NLEV * TOPN;   // 1500 candidates per image
constexpr int KROWS = 1536;          // padded rows for NMS bitmask
constexpr int WORDS = 24;            // 1536 / 64
constexpr int NTRI  = WORDS * (WORDS + 1) / 2;   // 300 lower-triangle tiles
constexpr int POSTN = 100;
constexpr int CAP   = 4096;          // per-(b,level) candidate pool
constexpr int NBINS = 2048;          // score-histogram bins over [0.25, 1.0)
constexpr int NPAIR = NLEV * NB;     // 80

constexpr int HW0 = 12800, HW1 = 3200, HW2 = 800, HW3 = 208, HW4 = 56;
constexpr int CH0 = 63, CH1 = 16, CH2 = 4, CH3 = 2, CH4 = 1;  // 16384-elem chunks per (b,level)
constexpr int CHUNKS = CH0 + CH1 + CH2 + CH3 + CH4;           // 86

// group-max skip list: 256-element groups, layout [li][b][g] (u16)
constexpr int GPL0 = 4000, GPL1 = 1000, GPL2 = 250, GPL3 = 65, GPL4 = 18;
constexpr int GMXB0 = 0;
constexpr int GMXB1 = GMXB0 + NB * GPL0;
constexpr int GMXB2 = GMXB1 + NB * GPL1;
constexpr int GMXB3 = GMXB2 + NB * GPL2;
constexpr int GMXB4 = GMXB3 + NB * GPL3;
constexpr int GMXN  = GMXB4 + NB * GPL4;

constexpr int BPP = 16;          // collect blocks per pid (max slice 4000/16=250 < THREADS)

// histogram floor per level: big levels (top-300 of >=64K elems) always threshold
// far above s=0.5 (bin 1024) -> skip ~90% of LDS atomics. Small levels keep floor 1.
constexpr int HF_BIG = 1024, HF_SMALL = 1;

// ---------------- workspace layout ----------------
constexpr size_t align256(size_t x) { return (x + 255) & ~(size_t)255; }
constexpr size_t OFF_HIST = 0;
constexpr size_t OFF_CNT  = OFF_HIST + (size_t)NPAIR * NBINS * 4;
constexpr size_t OFF_CAND = align256(OFF_CNT + (size_t)NPAIR * 4);
constexpr size_t OFF_CBOX = align256(OFF_CAND + (size_t)NPAIR * CAP * 8);
constexpr size_t OFF_CSC  = align256(OFF_CBOX + (size_t)NB * KC * 4 * 4);
constexpr size_t OFF_CLB  = align256(OFF_CSC  + (size_t)NB * KC * 4);
constexpr size_t OFF_M    = align256(OFF_CLB  + (size_t)NB * KC * 4);
constexpr size_t OFF_GMX  = align256(OFF_M + (size_t)NB * KROWS * WORDS * 8);
// total ~8.8 MB

struct Cand { float s; int i; };

// ---------------- helpers ----------------
__device__ __forceinline__ float sigm(float x) { return 1.0f / (1.0f + expf(-x)); }

// fast sigmoid (hw v_exp_f32 + v_rcp_f32, <=~4 ulp). Used ONLY for the histogram /
// skip-list (threshold selection): combined |approx key - exact key| <= 1 bin,
// compensated by Tv = TA-1 and the gmx+1 group gate. Collect/select use exact sigm().
__device__ __forceinline__ float sigf(float x) {
#if __has_builtin(__builtin_amdgcn_exp2f) && __has_builtin(__builtin_amdgcn_rcpf)
    float e = __builtin_amdgcn_exp2f(__fmul_rn(x, -1.44269504088896340736f));
    return __builtin_amdgcn_rcpf(__fadd_rn(1.0f, e));
#else
    return 1.0f / (1.0f + __expf(-x));
#endif
}

// monotone key over score in (0,1): 2048 bins over [0.25,1.0), everything below -> bin 0
__device__ __forceinline__ unsigned scoreKey(float s) {
    unsigned b = __float_as_uint(s);
    unsigned k = (b < 0x3E800000u) ? 0u : ((b - 0x3E800000u) >> 13);
    return (k > 2047u) ? 2047u : k;
}

__device__ __forceinline__ unsigned long long readlane64(unsigned long long v, int l) {
    unsigned lo = (unsigned)__builtin_amdgcn_readlane((int)(unsigned)(v & 0xffffffffull), l);
    unsigned hi = (unsigned)__builtin_amdgcn_readlane((int)(unsigned)(v >> 32), l);
    return ((unsigned long long)hi << 32) | lo;
}

__device__ void bitonicShared(float* ss, int* si, int N) {
    for (int k = 2; k <= N; k <<= 1) {
        for (int j = k >> 1; j > 0; j >>= 1) {
            __syncthreads();
            for (int i = threadIdx.x; i < N; i += blockDim.x) {
                int ixj = i ^ j;
                if (ixj > i) {
                    float s1 = ss[i], s2 = ss[ixj];
                    int a1 = si[i], a2 = si[ixj];
                    bool bef = (s1 > s2) || (s1 == s2 && a1 < a2);   // desc, idx asc
                    bool up = ((i & k) == 0);
                    if (up ? !bef : bef) { ss[i] = s2; ss[ixj] = s1; si[i] = a2; si[ixj] = a1; }
                }
            }
        }
    }
    __syncthreads();
}

// ---------------- K0: zero hist+cnt ----------------
__global__ __launch_bounds__(THREADS) void k_zero(unsigned* __restrict__ zp, int zn) {
    int i = blockIdx.x * THREADS + threadIdx.x;
    if (i < zn) zp[i] = 0;
}

// ---------------- K1: approx histogram + per-256-group max approx key ----------------
template<int HW, int GPL, int GMXB, int HF>
__device__ __forceinline__ void histChunkV(int chunkLocal, int b,
        const float* __restrict__ cls, const float* __restrict__ ctr,
        unsigned short* __restrict__ gmx, unsigned* __restrict__ h) {
    constexpr int NE = HW * NC;
    const float* cp = cls + (size_t)b * NE;
    const float* tb = ctr + (size_t)b * HW;
    unsigned short* gp = gmx + GMXB + (size_t)b * GPL;
    int w = threadIdx.x >> 6, lane = threadIdx.x & 63;
    int half = lane >> 5, hlane = lane & 31;
    for (int bi = w; bi < 32; bi += 4) {
        int ebase = (chunkLocal * 32 + bi) * 512;
        if (ebase >= NE) break;
        int e = ebase + lane * 8;
        int kmax = 0;
        if (e < NE) {   // NE%8==0 -> e<NE implies e+7<NE
            int c = e / HW; int hwb = e - c * HW;
            float4 xa = *(const float4*)(cp + e);
            float4 xb = *(const float4*)(cp + e + 4);
            float4 ta = *(const float4*)(tb + hwb);
            float4 tc = *(const float4*)(tb + hwb + 4);
            float xs[8] = {xa.x, xa.y, xa.z, xa.w, xb.x, xb.y, xb.z, xb.w};
            float ts[8] = {ta.x, ta.y, ta.z, ta.w, tc.x, tc.y, tc.z, tc.w};
            #pragma unroll
            for (int q = 0; q < 8; ++q) {
                float scls = sigf(xs[q]);                // FAST sigmoid (approx key)
                float s = __fmul_rn(scls, sigf(ts[q]));  // FAST sigmoid(ctr) inline
                unsigned key = scoreKey(s);
                if (key >= (unsigned)HF) atomicAdd(&h[key], 1u);
                kmax = max(kmax, (int)key);
            }
        }
        #pragma unroll
        for (int sh = 1; sh < 32; sh <<= 1) kmax = max(kmax, __shfl_xor(kmax, sh, 64));
        int g = (ebase >> 8) + half;
        if (hlane == 0 && g * 256 < NE) gp[g] = (unsigned short)kmax;
    }
}

__global__ __launch_bounds__(THREADS) void k_hist(
        const float* c0, const float* c1, const float* c2, const float* c3, const float* c4,
        const float* t0, const float* t1, const float* t2, const float* t3, const float* t4,
        unsigned short* __restrict__ gmx, unsigned* ghist) {
    __shared__ unsigned h[NBINS];
    for (int k = threadIdx.x; k < NBINS; k += THREADS) h[k] = 0;
    __syncthreads();
    int cx = blockIdx.x, b = blockIdx.y;
    int li;
    if (cx < CH0)                 { histChunkV<HW0,GPL0,GMXB0,HF_BIG>(cx, b, c0, t0, gmx, h); li = 0; }
    else if (cx < CH0+CH1)        { histChunkV<HW1,GPL1,GMXB1,HF_BIG>(cx-CH0, b, c1, t1, gmx, h); li = 1; }
    else if (cx < CH0+CH1+CH2)    { histChunkV<HW2,GPL2,GMXB2,HF_BIG>(cx-CH0-CH1, b, c2, t2, gmx, h); li = 2; }
    else if (cx < CH0+CH1+CH2+CH3){ histChunkV<HW3,GPL3,GMXB3,HF_SMALL>(cx-CH0-CH1-CH2, b, c3, t3, gmx, h); li = 3; }
    else                          { histChunkV<HW4,GPL4,GMXB4,HF_SMALL>(cx-CH0-CH1-CH2-CH3, b, c4, t4, gmx, h); li = 4; }
    __syncthreads();
    unsigned* gp = ghist + (size_t)(li * NB + b) * NBINS;
    for (int k = threadIdx.x; k < NBINS; k += THREADS) {
        unsigned v = h[k];
        if (v) atomicAdd(&gp[k], v);
    }
}

// ---------------- K2: fused threshold + slice-scan + compaction -----------------------
constexpr int LBUF = 1024;
constexpr int GB = 8;

template<int HW>
__device__ __forceinline__ void procList(int b, int pid, unsigned Tv, unsigned n,
        const unsigned short* __restrict__ glist,
        const float* __restrict__ cls, const float* __restrict__ ctr,
        Cand* __restrict__ cd, unsigned* __restrict__ cnt,
        Cand* __restrict__ lbuf, unsigned* __restrict__ lcnt) {
    constexpr int NE = HW * NC;
    const float* cp = cls + (size_t)b * NE;
    const float* tb = ctr + (size_t)b * HW;
    for (unsigned base = 0; base < n; base += GB) {
        float xv[GB], rv[GB];
        int ev[GB];
        bool okv[GB];
        #pragma unroll
        for (int q = 0; q < GB; ++q) {
            unsigned gi = base + q;
            int g = glist[(gi < n) ? gi : (n - 1)];   // n >= 1 guaranteed by caller
            int e = g * 256 + (int)threadIdx.x;
            bool ok = (gi < n) && (e < NE);
            e = ok ? e : 0;
            int c = e / HW; int hw = e - c * HW;
            xv[q] = cp[e];
            rv[q] = tb[hw];
            ev[q] = e;
            okv[q] = ok;
        }
        __builtin_amdgcn_sched_barrier(0);   // keep the 2*GB loads batched above the uses
        #pragma unroll
        for (int q = 0; q < GB; ++q) {
            float scls = sigm(xv[q]);                    // EXACT sigmoid(cls)
            float s = __fmul_rn(scls, sigm(rv[q]));      // EXACT sigmoid(ctr)
            unsigned key = scoreKey(s);
            bool take = okv[q] && (Tv ? (key >= Tv) : (scls > 0.05f));
            if (take) {
                int e = ev[q];
                int c = e / HW; int hw = e - c * HW;
                unsigned slot = atomicAdd(lcnt, 1u);
                if (slot < (unsigned)LBUF) { lbuf[slot].s = s; lbuf[slot].i = hw * NC + c; }
                else {
                    unsigned gs = atomicAdd(&cnt[pid], 1u);   // rare fallback
                    if (gs < (unsigned)CAP) { cd[gs].s = s; cd[gs].i = hw * NC + c; }
                }
            }
        }
    }
}

__global__ __launch_bounds__(THREADS) void k_collect(
        const float* c0, const float* c1, const float* c2, const float* c3, const float* c4,
        const float* t0, const float* t1, const float* t2, const float* t3, const float* t4,
        const unsigned* __restrict__ ghist, const unsigned short* __restrict__ gmx,
        Cand* cand, unsigned* cnt) {
    __shared__ unsigned sfx[THREADS];
    __shared__ int tstar;
    __shared__ unsigned shTv;
    __shared__ Cand lbuf[LBUF];
    __shared__ unsigned lcnt, gbase, gcnt;
    __shared__ unsigned short glist[THREADS];
    int tid = (int)threadIdx.x;
    int pid = blockIdx.y;
    int li = pid >> 4, b = pid & 15;
    if (tid == 0) { lcnt = 0; gcnt = 0; tstar = -1; }

    // ---- Tv: parallel suffix-scan over 256 8-bin segments
    const unsigned* h = ghist + (size_t)pid * NBINS;
    unsigned s = 0;
    #pragma unroll
    for (int k = 0; k < 8; ++k) s += h[tid * 8 + k];
    sfx[tid] = s;
    for (int d = 1; d < THREADS; d <<= 1) {
        __syncthreads();
        unsigned v = (tid + d < THREADS) ? sfx[tid + d] : 0u;
        __syncthreads();
        sfx[tid] += v;
    }
    __syncthreads();
    if (sfx[tid] >= (unsigned)TOPN && (tid == THREADS - 1 || sfx[tid + 1] < (unsigned)TOPN))
        tstar = tid;   // sfx non-increasing -> unique
    __syncthreads();
    if (tid == 0) {
        unsigned TA = 0;
        int t = tstar;
        if (t >= 0) {
            unsigned acc = (t < THREADS - 1) ? sfx[t + 1] : 0u;
            int lo = t * 8, bin = lo + 7;
            for (; bin >= lo; --bin) { acc += h[bin]; if (acc >= (unsigned)TOPN) break; }
            TA = (unsigned)max(bin, lo);
        }
        shTv = (TA >= 1) ? (TA - 1) : 0u;   // 0 => degenerate fallback
    }
    __syncthreads();
    unsigned Tv = shTv;

    // ---- static gmx slice -> ballot-compacted local group list
    int GPL, GMXB;
    switch (li) {
        case 0: GPL = GPL0; GMXB = GMXB0; break;
        case 1: GPL = GPL1; GMXB = GMXB1; break;
        case 2: GPL = GPL2; GMXB = GMXB2; break;
        case 3: GPL = GPL3; GMXB = GMXB3; break;
        default: GPL = GPL4; GMXB = GMXB4; break;
    }
    const unsigned short* gp = gmx + GMXB + (size_t)b * GPL;
    int per = (GPL + BPP - 1) / BPP;
    int lo = (int)blockIdx.x * per;
    int hi = min(GPL, lo + per);
    {
        int g = lo + tid;
        bool ok = (g < hi);
        if (ok && Tv) ok = ((unsigned)gp[g] + 1u >= Tv);   // gmx is max APPROX key: +1 slack
        unsigned long long m = __ballot(ok);
        int nW = __popcll(m);
        if (nW) {
            unsigned wb = 0;
            if ((tid & 63) == 0) wb = atomicAdd(&gcnt, (unsigned)nW);   // LDS atomic
            wb = (unsigned)__builtin_amdgcn_readfirstlane((int)wb);
            if (ok) glist[wb + (unsigned)__popcll(m & ((1ull << (tid & 63)) - 1ull))] = (unsigned short)g;
        }
    }
    __syncthreads();
    unsigned n = gcnt;
    Cand* cd = cand + (size_t)pid * CAP;
    if (n) {
        switch (li) {
            case 0: procList<HW0>(b, pid, Tv, n, glist, c0, t0, cd, cnt, lbuf, &lcnt); break;
            case 1: procList<HW1>(b, pid, Tv, n, glist, c1, t1, cd, cnt, lbuf, &lcnt); break;
            case 2: procList<HW2>(b, pid, Tv, n, glist, c2, t2, cd, cnt, lbuf, &lcnt); break;
            case 3: procList<HW3>(b, pid, Tv, n, glist, c3, t3, cd, cnt, lbuf, &lcnt); break;
            default: procList<HW4>(b, pid, Tv, n, glist, c4, t4, cd, cnt, lbuf, &lcnt); break;
        }
    }
    __syncthreads();
    unsigned nl = lcnt; if (nl > (unsigned)LBUF) nl = LBUF;
    if (tid == 0) gbase = nl ? atomicAdd(&cnt[pid], nl) : 0u;
    __syncthreads();
    for (unsigned i = tid; i < nl; i += THREADS) {
        unsigned sl = gbase + i;
        if (sl < (unsigned)CAP) cd[sl] = lbuf[i];
    }
}

// ---------------- K3: exact top-300 per (b,level) + decode (bitonic) ----------
__global__ __launch_bounds__(THREADS) void k_select(
        const Cand* __restrict__ candAll, const unsigned* __restrict__ cntAll,
        const float* l0, const float* l1, const float* l2, const float* l3, const float* l4,
        const float* b0, const float* b1, const float* b2, const float* b3, const float* b4,
        float* __restrict__ cbox, float* __restrict__ csc, int* __restrict__ clb) {
    __shared__ float ss[CAP];
    __shared__ int si[CAP];
    int pid = blockIdx.x;
    int li = pid / NB, b = pid - li * NB;
    int n = (int)min(cntAll[pid], (unsigned)CAP);
    const Cand* cd = candAll + (size_t)pid * CAP;
    int N = 2; while (N < n) N <<= 1;
    for (int k = threadIdx.x; k < N; k += THREADS) {
        if (k < n) { ss[k] = cd[k].s; si[k] = cd[k].i; }
        else       { ss[k] = -INFINITY; si[k] = 0x40000000 + k; }
    }
    __syncthreads();
    bitonicShared(ss, si, N);

    const float* locp; const float* boxp; int HW;
    switch (li) {
        case 0: locp = l0; boxp = b0; HW = HW0; break;
        case 1: locp = l1; boxp = b1; HW = HW1; break;
        case 2: locp = l2; boxp = b2; HW = HW2; break;
        case 3: locp = l3; boxp = b3; HW = HW3; break;
        default: locp = l4; boxp = b4; HW = HW4; break;
    }
    for (int j = threadIdx.x; j < TOPN; j += THREADS) {
        int cidx = b * KC + li * TOPN + j;
        bool ok = (j < n);
        float s = ok ? ss[j] : -INFINITY;
        ok = ok && (s > 0.0f);
        if (ok) {
            int idx = si[j];
            int hw = idx / NC, c = idx - hw * NC;
            float lx = locp[hw * 2 + 0], ly = locp[hw * 2 + 1];
            const float* bp = boxp + (size_t)b * 4 * HW + hw;
            float bl = bp[0], bt = bp[HW], br = bp[2 * HW], bb = bp[3 * HW];
            float x1 = fminf(fmaxf(__fsub_rn(lx, bl), 0.0f), 1023.0f);
            float y1 = fminf(fmaxf(__fsub_rn(ly, bt), 0.0f),  799.0f);
            float x2 = fminf(fmaxf(__fadd_rn(lx, br), 0.0f), 1023.0f);
            float y2 = fminf(fmaxf(__fadd_rn(ly, bb), 0.0f),  799.0f);
            cbox[cidx * 4 + 0] = x1; cbox[cidx * 4 + 1] = y1;
            cbox[cidx * 4 + 2] = x2; cbox[cidx * 4 + 3] = y2;
            csc[cidx] = sqrtf(fmaxf(s, 1e-12f));
            clb[cidx] = c + 1;
        } else {
            cbox[cidx * 4 + 0] = 0.0f; cbox[cidx * 4 + 1] = 0.0f;
            cbox[cidx * 4 + 2] = 0.0f; cbox[cidx * 4 + 3] = 0.0f;
            csc[cidx] = -INFINITY;
            clb[cidx] = 0;
        }
    }
}

// ---------------- K4: fused per-image finale: merge + IoU + greedy NMS ---------------
// One block per image, 1024 threads. All per-image intermediates (sorted scores,
// labels, boxes, offset boxes, areas) live in LDS only (~72 KB) — no grid barrier
// needed because every consumer is in the same block. MT stays global (294 KB/image).
__global__ __launch_bounds__(1024) void k_final(
        const float* __restrict__ csc, const int* __restrict__ clb,
        const float* __restrict__ cbox,
        unsigned long long* __restrict__ MT, float* __restrict__ out) {
    __shared__ float  sin_l[KC];     // input csc copy (level-major)
    __shared__ float  ssc_l[KC];     // sorted scores
    __shared__ int    slb_l[KC];     // sorted labels
    __shared__ float4 sbox_l[KC];    // sorted boxes
    __shared__ float4 obox_l[KC];    // sorted boxes + class offset
    __shared__ float  area_l[KC];    // areas of offset boxes
    int b = blockIdx.x;
    int tid = (int)threadIdx.x;

    // ---- phase A: 5-way merge by rank (identical math to round-5 k_merge) ----
    for (int k = tid; k < KC; k += 1024) sin_l[k] = csc[b * KC + k];
    __syncthreads();
    for (int k = tid; k < KC; k += 1024) {
        int li = k / TOPN, j = k - li * TOPN;
        float s = sin_l[k];
        int rank = j;
        #pragma unroll
        for (int l = 0; l < NLEV; ++l) {
            if (l == li) continue;
            const float* seg = sin_l + l * TOPN;
            int lo = 0, hi = TOPN;
            if (l < li) {
                while (lo < hi) { int m = (lo + hi) >> 1; if (seg[m] >= s) lo = m + 1; else hi = m; }
            } else {
                while (lo < hi) { int m = (lo + hi) >> 1; if (seg[m] >  s) lo = m + 1; else hi = m; }
            }
            rank += lo;
        }
        int src = b * KC + k;
        int lab = clb[src];
        ssc_l[rank] = s;
        slb_l[rank] = lab;
        float off = __fmul_rn((float)lab, 1025.0f);   // offset = max(800,1024)+1
        float4 v = *(const float4*)&cbox[(size_t)src * 4];
        sbox_l[rank] = v;
        float4 o;
        o.x = __fadd_rn(v.x, off); o.y = __fadd_rn(v.y, off);
        o.z = __fadd_rn(v.z, off); o.w = __fadd_rn(v.w, off);
        obox_l[rank] = o;
        area_l[rank] = __fmul_rn(__fsub_rn(o.z, o.x), __fsub_rn(o.w, o.y));
    }
    __syncthreads();

    // ---- phase B: triangular IoU tiles from LDS boxes (wave-parallel) ----
    int wid = tid >> 6, lane = tid & 63;
    for (int t = wid; t < NTRI; t += 16) {
        int tile = 0, rem = t;
        while (rem >= WORDS - tile) { rem -= WORDS - tile; ++tile; }
        int w = tile + rem;
        int j0 = w * 64;
        int i = tile * 64 + lane;
        int ic = (i < KC) ? i : (KC - 1);
        float4 bi = obox_l[ic];
        float ai = area_l[ic];
        unsigned long long bits = 0;
        int jmax = min(64, KC - j0);
        for (int jj = 0; jj < jmax; ++jj) {
            float4 bj = obox_l[j0 + jj];   // wave-uniform -> LDS broadcast
            float xx1 = fmaxf(bi.x, bj.x), yy1 = fmaxf(bi.y, bj.y);
            float xx2 = fminf(bi.z, bj.z), yy2 = fminf(bi.w, bj.w);
            float ww = fmaxf(__fsub_rn(xx2, xx1), 0.0f);
            float hh = fmaxf(__fsub_rn(yy2, yy1), 0.0f);
            float inter = __fmul_rn(ww, hh);
            float uni = __fsub_rn(__fadd_rn(ai, area_l[j0 + jj]), inter);
            float iou = __fdiv_rn(inter, fmaxf(uni, 1e-9f));
            bool kp = ((j0 + jj) > i) && (iou > 0.6f);
            bits |= kp ? (1ull << jj) : 0ull;
        }
        if (i >= KC) bits = 0;
        MT[((size_t)b * WORDS + w) * KROWS + i] = bits;
    }
    __syncthreads();   // drains vmcnt -> MT writes visible to this block's wave 0

    // ---- phase C: greedy NMS scan (wave 0 only), early-exit at POSTN kept ----
    if (tid < 64) {
        for (int k = lane; k < POSTN * 5; k += 64) out[(size_t)b * POSTN * 5 + k] = 0.0f;
        for (int k = lane; k < POSTN; k += 64) {
            out[(size_t)NB * POSTN * 5 + b * POSTN + k] = 0.0f;                 // labels
            out[(size_t)NB * POSTN * 5 + NB * POSTN + b * POSTN + k] = 0.0f;    // valid
        }
        unsigned long long validV = 0;
        for (int c = 0; c < WORDS; ++c) {
            int i = c * 64 + lane;
            bool f = (i < KC) && (ssc_l[i] > 0.0f);
            unsigned long long m = __ballot(f);
            validV = (lane == c) ? m : validV;
        }
        unsigned long long mybit = 1ull << lane;
        unsigned long long keptV = 0;
        const unsigned long long* Mb = MT + (size_t)b * WORDS * KROWS;

        unsigned long long pv[WORDS];
        pv[0] = Mb[lane];

        int keptTotal = 0;
        for (int t = 0; t < WORDS; ++t) {
            int tn = (t + 1 < WORDS) ? (t + 1) : t;
            const unsigned long long* cp = Mb + (size_t)tn * KROWS + lane;
            unsigned long long nv[WORDS];
            #pragma unroll
            for (int c = 0; c < WORDS; ++c) {
                int cc = (c <= tn) ? c : 0;
                nv[c] = cp[(size_t)cc * 64];
            }
            __builtin_amdgcn_sched_barrier(0);    // loads stay above; compute below

            unsigned long long D = pv[t];
            unsigned long long acc = 0;
            #pragma unroll
            for (int c = 0; c < WORDS; ++c) {
                if (c < t) {
                    unsigned long long kc = readlane64(keptV, c);
                    if (kc & mybit) acc |= pv[c];
                }
            }
            #pragma unroll
            for (int s = 1; s < 64; s <<= 1) acc |= __shfl_xor(acc, s, 64);

            unsigned long long validT = readlane64(validV, t);
            unsigned long long rem = acc;
            unsigned long long sup = __ballot(D != 0ull) & validT;
            unsigned long long todoS = sup;
            while (todoS) {
                int r = __builtin_ctzll(todoS);
                todoS &= todoS - 1;
                if (!((rem >> r) & 1ull)) {
                    unsigned long long Dr = readlane64(D, r);
                    rem |= Dr;
                    todoS &= ~Dr;
                }
            }
            unsigned long long kept = validT & ~rem;
            keptV = (lane == t) ? kept : keptV;

            keptTotal += (int)__popcll(kept);      // kept is wave-uniform
            if (keptTotal >= POSTN) break;         // first POSTN kept fully determined

            #pragma unroll
            for (int c = 0; c < WORDS; ++c) pv[c] = nv[c];
        }

        int base = 0;
        for (int c = 0; c < WORDS && base < POSTN; ++c) {
            unsigned long long kw = readlane64(keptV, c);
            bool f = (kw & mybit) != 0ull;
            int rank = base + __popcll(kw & (mybit - 1ull));
            if (f && rank < POSTN) {
                int i = c * 64 + lane;
                float4 v = sbox_l[i];
                float* o5 = out + ((size_t)b * POSTN + rank) * 5;
                o5[0] = v.x; o5[1] = v.y; o5[2] = v.z; o5[3] = v.w;
                o5[4] = ssc_l[i];
                out[(size_t)NB * POSTN * 5 + b * POSTN + rank] = (float)slb_l[i];
                out[(size_t)NB * POSTN * 5 + NB * POSTN + b * POSTN + rank] = 1.0f;
            }
            base += __popcll(kw);
        }
    }
}

// ---------------- launch (5 dispatches, was 7) ----------------
extern "C" void kernel_launch(void* const* d_in, const int* in_sizes, int n_in,
                              void* d_out, int out_size, void* d_ws, size_t ws_size,
                              hipStream_t stream) {
    const float *loc[5], *cls[5], *box[5], *ctr[5];
    for (int l = 0; l < 5; ++l) {
        loc[l] = (const float*)d_in[l * 4 + 0];
        cls[l] = (const float*)d_in[l * 4 + 1];
        box[l] = (const float*)d_in[l * 4 + 2];
        ctr[l] = (const float*)d_in[l * 4 + 3];
    }
    char* ws = (char*)d_ws;
    unsigned* hist = (unsigned*)(ws + OFF_HIST);
    unsigned* cnt  = (unsigned*)(ws + OFF_CNT);
    Cand* cand     = (Cand*)(ws + OFF_CAND);
    float* cbox    = (float*)(ws + OFF_CBOX);
    float* csc     = (float*)(ws + OFF_CSC);
    int*   clb     = (int*)(ws + OFF_CLB);
    unsigned long long* MT = (unsigned long long*)(ws + OFF_M);
    unsigned short* gmx = (unsigned short*)(ws + OFF_GMX);
    float* out = (float*)d_out;

    int zn = (int)(OFF_CAND / 4);
    k_zero<<<(zn + THREADS - 1) / THREADS, THREADS, 0, stream>>>((unsigned*)ws, zn);
    k_hist<<<dim3(CHUNKS, NB), THREADS, 0, stream>>>(
        cls[0], cls[1], cls[2], cls[3], cls[4],
        ctr[0], ctr[1], ctr[2], ctr[3], ctr[4], gmx, hist);
    k_collect<<<dim3(BPP, NPAIR), THREADS, 0, stream>>>(
        cls[0], cls[1], cls[2], cls[3], cls[4],
        ctr[0], ctr[1], ctr[2], ctr[3], ctr[4], hist, gmx, cand, cnt);
    k_select<<<NPAIR, THREADS, 0, stream>>>(
        cand, cnt,
        loc[0], loc[1], loc[2], loc[3], loc[4],
        box[0], box[1], box[2], box[3], box[4],
        cbox, csc, clb);
    k_final<<<NB, 1024, 0, stream>>>(csc, clb, cbox, MT, out);
}

// Round 8
// 234.403 us; speedup vs baseline: 3.3407x; 2.0082x over previous
//
#include <hip/hip_runtime.h>
#include <math.h>

#define THREADS 256
#define SELT 512

// ---------------- problem constants (fixed by reference setup) ----------------
constexpr int NLEV  = 5;
constexpr int NB    = 16;     // batch
constexpr int NC    = 80;     // classes (label = c+1)
constexpr int TOPN  = 300;
constexpr int KC    = NLEV * TOPN;   // 1500 candidates per image
constexpr int KROWS = 1536;          // padded rows for NMS bitmask
constexpr int WORDS = 24;            // 1536 / 64
constexpr int NTRI  = WORDS * (WORDS + 1) / 2;   // 300 lower-triangle tiles
constexpr int POSTN = 100;
constexpr int CAP   = 4096;          // per-(b,level) candidate pool
constexpr int NBINS = 2048;          // score-histogram bins over [0.25, 1.0)
constexpr int NPAIR = NLEV * NB;     // 80

constexpr int HW0 = 12800, HW1 = 3200, HW2 = 800, HW3 = 208, HW4 = 56;
constexpr int CH0 = 63, CH1 = 16, CH2 = 4, CH3 = 2, CH4 = 1;  // 16384-elem chunks per (b,level)
constexpr int CHUNKS = CH0 + CH1 + CH2 + CH3 + CH4;           // 86

// group-max skip list: 256-element groups, layout [li][b][g] (u16)
constexpr int GPL0 = 4000, GPL1 = 1000, GPL2 = 250, GPL3 = 65, GPL4 = 18;
constexpr int GMXB0 = 0;
constexpr int GMXB1 = GMXB0 + NB * GPL0;
constexpr int GMXB2 = GMXB1 + NB * GPL1;
constexpr int GMXB3 = GMXB2 + NB * GPL2;
constexpr int GMXB4 = GMXB3 + NB * GPL3;
constexpr int GMXN  = GMXB4 + NB * GPL4;

constexpr int BPP = 16;          // collect blocks per pid (max slice 4000/16=250 < THREADS)

// histogram floor per level: big levels (top-300 of >=64K elems) always threshold
// far above s=0.5 (bin 1024) -> skip ~90% of LDS atomics. Small levels keep floor 1.
constexpr int HF_BIG = 1024, HF_SMALL = 1;

// ---------------- workspace layout ----------------
constexpr size_t align256(size_t x) { return (x + 255) & ~(size_t)255; }
constexpr size_t OFF_HIST = 0;
constexpr size_t OFF_CNT  = OFF_HIST + (size_t)NPAIR * NBINS * 4;
constexpr size_t OFF_CAND = align256(OFF_CNT + (size_t)NPAIR * 4);
constexpr size_t OFF_CBOX = align256(OFF_CAND + (size_t)NPAIR * CAP * 8);
constexpr size_t OFF_CSC  = align256(OFF_CBOX + (size_t)NB * KC * 4 * 4);
constexpr size_t OFF_CLB  = align256(OFF_CSC  + (size_t)NB * KC * 4);
constexpr size_t OFF_SSC  = align256(OFF_CLB  + (size_t)NB * KC * 4);
constexpr size_t OFF_SLB  = align256(OFF_SSC  + (size_t)NB * KC * 4);
constexpr size_t OFF_SBOX = align256(OFF_SLB  + (size_t)NB * KC * 4);
constexpr size_t OFF_OBOX = align256(OFF_SBOX + (size_t)NB * KC * 4 * 4);
constexpr size_t OFF_M    = align256(OFF_OBOX + (size_t)NB * KC * 4 * 4);
constexpr size_t OFF_GMX  = align256(OFF_M + (size_t)NB * KROWS * WORDS * 8);
// total ~9.7 MB

struct Cand { float s; int i; };

// ---------------- helpers ----------------
__device__ __forceinline__ float sigm(float x) { return 1.0f / (1.0f + expf(-x)); }

// fast fused product sigm(x)*sigm(t) = 1/((1+e^-x)(1+e^-t)) with ONE rcp.
// Used ONLY for the histogram / skip-list (threshold selection): combined
// |approx key - exact key| <= 1 bin (bins are 2^13 ulp wide; hw exp2/rcp are
// ~1 ulp each), compensated by Tv = TA-1 and the gmx+1 group gate.
// Collect/select use exact sigm() -> output bit-identical.
__device__ __forceinline__ float sig2f(float x, float t) {
#if __has_builtin(__builtin_amdgcn_exp2f) && __has_builtin(__builtin_amdgcn_rcpf)
    float ea = __builtin_amdgcn_exp2f(__fmul_rn(x, -1.44269504088896340736f));
    float eb = __builtin_amdgcn_exp2f(__fmul_rn(t, -1.44269504088896340736f));
    // x very negative -> ea large/inf -> product inf -> rcp = 0 -> key 0 (safe)
    return __builtin_amdgcn_rcpf(__fmul_rn(__fadd_rn(1.0f, ea), __fadd_rn(1.0f, eb)));
#else
    return (1.0f / (1.0f + __expf(-x))) * (1.0f / (1.0f + __expf(-t)));
#endif
}

// monotone key over score in (0,1): 2048 bins over [0.25,1.0), everything below -> bin 0
__device__ __forceinline__ unsigned scoreKey(float s) {
    unsigned b = __float_as_uint(s);
    unsigned k = (b < 0x3E800000u) ? 0u : ((b - 0x3E800000u) >> 13);
    return (k > 2047u) ? 2047u : k;
}

__device__ __forceinline__ unsigned long long readlane64(unsigned long long v, int l) {
    unsigned lo = (unsigned)__builtin_amdgcn_readlane((int)(unsigned)(v & 0xffffffffull), l);
    unsigned hi = (unsigned)__builtin_amdgcn_readlane((int)(unsigned)(v >> 32), l);
    return ((unsigned long long)hi << 32) | lo;
}

__device__ void bitonicShared(float* ss, int* si, int N) {
    for (int k = 2; k <= N; k <<= 1) {
        for (int j = k >> 1; j > 0; j >>= 1) {
            __syncthreads();
            for (int i = threadIdx.x; i < N; i += blockDim.x) {
                int ixj = i ^ j;
                if (ixj > i) {
                    float s1 = ss[i], s2 = ss[ixj];
                    int a1 = si[i], a2 = si[ixj];
                    bool bef = (s1 > s2) || (s1 == s2 && a1 < a2);   // desc, idx asc
                    bool up = ((i & k) == 0);
                    if (up ? !bef : bef) { ss[i] = s2; ss[ixj] = s1; si[i] = a2; si[ixj] = a1; }
                }
            }
        }
    }
    __syncthreads();
}

// ---------------- K0: zero hist+cnt ----------------
__global__ __launch_bounds__(THREADS) void k_zero(unsigned* __restrict__ zp, int zn) {
    int i = blockIdx.x * THREADS + threadIdx.x;
    if (i < zn) zp[i] = 0;
}

// ---------------- K1: approx histogram + per-256-group max approx key ----------------
template<int HW, int GPL, int GMXB, int HF>
__device__ __forceinline__ void histChunkV(int chunkLocal, int b,
        const float* __restrict__ cls, const float* __restrict__ ctr,
        unsigned short* __restrict__ gmx, unsigned* __restrict__ h) {
    constexpr int NE = HW * NC;
    const float* cp = cls + (size_t)b * NE;
    const float* tb = ctr + (size_t)b * HW;
    unsigned short* gp = gmx + GMXB + (size_t)b * GPL;
    int w = threadIdx.x >> 6, lane = threadIdx.x & 63;
    int half = lane >> 5, hlane = lane & 31;
    for (int bi = w; bi < 32; bi += 4) {
        int ebase = (chunkLocal * 32 + bi) * 512;
        if (ebase >= NE) break;
        int e = ebase + lane * 8;
        int kmax = 0;
        if (e < NE) {   // NE%8==0 -> e<NE implies e+7<NE
            int c = e / HW; int hwb = e - c * HW;
            float4 xa = *(const float4*)(cp + e);
            float4 xb = *(const float4*)(cp + e + 4);
            float4 ta = *(const float4*)(tb + hwb);
            float4 tc = *(const float4*)(tb + hwb + 4);
            float xs[8] = {xa.x, xa.y, xa.z, xa.w, xb.x, xb.y, xb.z, xb.w};
            float ts[8] = {ta.x, ta.y, ta.z, ta.w, tc.x, tc.y, tc.z, tc.w};
            #pragma unroll
            for (int q = 0; q < 8; ++q) {
                float s = sig2f(xs[q], ts[q]);           // FAST fused sigmoid product
                unsigned key = scoreKey(s);
                if (key >= (unsigned)HF) atomicAdd(&h[key], 1u);
                kmax = max(kmax, (int)key);
            }
        }
        #pragma unroll
        for (int sh = 1; sh < 32; sh <<= 1) kmax = max(kmax, __shfl_xor(kmax, sh, 64));
        int g = (ebase >> 8) + half;
        if (hlane == 0 && g * 256 < NE) gp[g] = (unsigned short)kmax;
    }
}

__global__ __launch_bounds__(THREADS) void k_hist(
        const float* c0, const float* c1, const float* c2, const float* c3, const float* c4,
        const float* t0, const float* t1, const float* t2, const float* t3, const float* t4,
        unsigned short* __restrict__ gmx, unsigned* ghist) {
    __shared__ unsigned h[NBINS];
    for (int k = threadIdx.x; k < NBINS; k += THREADS) h[k] = 0;
    __syncthreads();
    int cx = blockIdx.x, b = blockIdx.y;
    int li;
    if (cx < CH0)                 { histChunkV<HW0,GPL0,GMXB0,HF_BIG>(cx, b, c0, t0, gmx, h); li = 0; }
    else if (cx < CH0+CH1)        { histChunkV<HW1,GPL1,GMXB1,HF_BIG>(cx-CH0, b, c1, t1, gmx, h); li = 1; }
    else if (cx < CH0+CH1+CH2)    { histChunkV<HW2,GPL2,GMXB2,HF_BIG>(cx-CH0-CH1, b, c2, t2, gmx, h); li = 2; }
    else if (cx < CH0+CH1+CH2+CH3){ histChunkV<HW3,GPL3,GMXB3,HF_SMALL>(cx-CH0-CH1-CH2, b, c3, t3, gmx, h); li = 3; }
    else                          { histChunkV<HW4,GPL4,GMXB4,HF_SMALL>(cx-CH0-CH1-CH2-CH3, b, c4, t4, gmx, h); li = 4; }
    __syncthreads();
    unsigned* gp = ghist + (size_t)(li * NB + b) * NBINS;
    for (int k = threadIdx.x; k < NBINS; k += THREADS) {
        unsigned v = h[k];
        if (v) atomicAdd(&gp[k], v);
    }
}

// ---------------- K2: fused threshold + slice-scan + compaction -----------------------
constexpr int LBUF = 1024;
constexpr int GB = 8;

template<int HW>
__device__ __forceinline__ void procList(int b, int pid, unsigned Tv, unsigned n,
        const unsigned short* __restrict__ glist,
        const float* __restrict__ cls, const float* __restrict__ ctr,
        Cand* __restrict__ cd, unsigned* __restrict__ cnt,
        Cand* __restrict__ lbuf, unsigned* __restrict__ lcnt) {
    constexpr int NE = HW * NC;
    const float* cp = cls + (size_t)b * NE;
    const float* tb = ctr + (size_t)b * HW;
    for (unsigned base = 0; base < n; base += GB) {
        float xv[GB], rv[GB];
        int ev[GB];
        bool okv[GB];
        #pragma unroll
        for (int q = 0; q < GB; ++q) {
            unsigned gi = base + q;
            int g = glist[(gi < n) ? gi : (n - 1)];   // n >= 1 guaranteed by caller
            int e = g * 256 + (int)threadIdx.x;
            bool ok = (gi < n) && (e < NE);
            e = ok ? e : 0;
            int c = e / HW; int hw = e - c * HW;
            xv[q] = cp[e];
            rv[q] = tb[hw];
            ev[q] = e;
            okv[q] = ok;
        }
        __builtin_amdgcn_sched_barrier(0);   // keep the 2*GB loads batched above the uses
        #pragma unroll
        for (int q = 0; q < GB; ++q) {
            float scls = sigm(xv[q]);                    // EXACT sigmoid(cls)
            float s = __fmul_rn(scls, sigm(rv[q]));      // EXACT sigmoid(ctr)
            unsigned key = scoreKey(s);
            bool take = okv[q] && (Tv ? (key >= Tv) : (scls > 0.05f));
            if (take) {
                int e = ev[q];
                int c = e / HW; int hw = e - c * HW;
                unsigned slot = atomicAdd(lcnt, 1u);
                if (slot < (unsigned)LBUF) { lbuf[slot].s = s; lbuf[slot].i = hw * NC + c; }
                else {
                    unsigned gs = atomicAdd(&cnt[pid], 1u);   // rare fallback
                    if (gs < (unsigned)CAP) { cd[gs].s = s; cd[gs].i = hw * NC + c; }
                }
            }
        }
    }
}

__global__ __launch_bounds__(THREADS) void k_collect(
        const float* c0, const float* c1, const float* c2, const float* c3, const float* c4,
        const float* t0, const float* t1, const float* t2, const float* t3, const float* t4,
        const unsigned* __restrict__ ghist, const unsigned short* __restrict__ gmx,
        Cand* cand, unsigned* cnt) {
    __shared__ unsigned sfx[THREADS];
    __shared__ int tstar;
    __shared__ unsigned shTv;
    __shared__ Cand lbuf[LBUF];
    __shared__ unsigned lcnt, gbase, gcnt;
    __shared__ unsigned short glist[THREADS];
    int tid = (int)threadIdx.x;
    int pid = blockIdx.y;
    int li = pid >> 4, b = pid & 15;
    if (tid == 0) { lcnt = 0; gcnt = 0; tstar = -1; }

    // ---- Tv: parallel suffix-scan over 256 8-bin segments
    const unsigned* h = ghist + (size_t)pid * NBINS;
    unsigned s = 0;
    #pragma unroll
    for (int k = 0; k < 8; ++k) s += h[tid * 8 + k];
    sfx[tid] = s;
    for (int d = 1; d < THREADS; d <<= 1) {
        __syncthreads();
        unsigned v = (tid + d < THREADS) ? sfx[tid + d] : 0u;
        __syncthreads();
        sfx[tid] += v;
    }
    __syncthreads();
    if (sfx[tid] >= (unsigned)TOPN && (tid == THREADS - 1 || sfx[tid + 1] < (unsigned)TOPN))
        tstar = tid;   // sfx non-increasing -> unique
    __syncthreads();
    if (tid == 0) {
        unsigned TA = 0;
        int t = tstar;
        if (t >= 0) {
            unsigned acc = (t < THREADS - 1) ? sfx[t + 1] : 0u;
            int lo = t * 8, bin = lo + 7;
            for (; bin >= lo; --bin) { acc += h[bin]; if (acc >= (unsigned)TOPN) break; }
            TA = (unsigned)max(bin, lo);
        }
        shTv = (TA >= 1) ? (TA - 1) : 0u;   // 0 => degenerate fallback
    }
    __syncthreads();
    unsigned Tv = shTv;

    // ---- static gmx slice -> ballot-compacted local group list
    int GPL, GMXB;
    switch (li) {
        case 0: GPL = GPL0; GMXB = GMXB0; break;
        case 1: GPL = GPL1; GMXB = GMXB1; break;
        case 2: GPL = GPL2; GMXB = GMXB2; break;
        case 3: GPL = GPL3; GMXB = GMXB3; break;
        default: GPL = GPL4; GMXB = GMXB4; break;
    }
    const unsigned short* gp = gmx + GMXB + (size_t)b * GPL;
    int per = (GPL + BPP - 1) / BPP;
    int lo = (int)blockIdx.x * per;
    int hi = min(GPL, lo + per);
    {
        int g = lo + tid;
        bool ok = (g < hi);
        if (ok && Tv) ok = ((unsigned)gp[g] + 1u >= Tv);   // gmx is max APPROX key: +1 slack
        unsigned long long m = __ballot(ok);
        int nW = __popcll(m);
        if (nW) {
            unsigned wb = 0;
            if ((tid & 63) == 0) wb = atomicAdd(&gcnt, (unsigned)nW);   // LDS atomic
            wb = (unsigned)__builtin_amdgcn_readfirstlane((int)wb);
            if (ok) glist[wb + (unsigned)__popcll(m & ((1ull << (tid & 63)) - 1ull))] = (unsigned short)g;
        }
    }
    __syncthreads();
    unsigned n = gcnt;
    Cand* cd = cand + (size_t)pid * CAP;
    if (n) {
        switch (li) {
            case 0: procList<HW0>(b, pid, Tv, n, glist, c0, t0, cd, cnt, lbuf, &lcnt); break;
            case 1: procList<HW1>(b, pid, Tv, n, glist, c1, t1, cd, cnt, lbuf, &lcnt); break;
            case 2: procList<HW2>(b, pid, Tv, n, glist, c2, t2, cd, cnt, lbuf, &lcnt); break;
            case 3: procList<HW3>(b, pid, Tv, n, glist, c3, t3, cd, cnt, lbuf, &lcnt); break;
            default: procList<HW4>(b, pid, Tv, n, glist, c4, t4, cd, cnt, lbuf, &lcnt); break;
        }
    }
    __syncthreads();
    unsigned nl = lcnt; if (nl > (unsigned)LBUF) nl = LBUF;
    if (tid == 0) gbase = nl ? atomicAdd(&cnt[pid], nl) : 0u;
    __syncthreads();
    for (unsigned i = tid; i < nl; i += THREADS) {
        unsigned sl = gbase + i;
        if (sl < (unsigned)CAP) cd[sl] = lbuf[i];
    }
}

// ---------------- K3: exact top-300 per (b,level) + decode (bitonic, 512 thr) --------
__global__ __launch_bounds__(SELT) void k_select(
        const Cand* __restrict__ candAll, const unsigned* __restrict__ cntAll,
        const float* l0, const float* l1, const float* l2, const float* l3, const float* l4,
        const float* b0, const float* b1, const float* b2, const float* b3, const float* b4,
        float* __restrict__ cbox, float* __restrict__ csc, int* __restrict__ clb) {
    __shared__ float ss[CAP];
    __shared__ int si[CAP];
    int pid = blockIdx.x;
    int li = pid / NB, b = pid - li * NB;
    int n = (int)min(cntAll[pid], (unsigned)CAP);
    const Cand* cd = candAll + (size_t)pid * CAP;
    int N = 2; while (N < n) N <<= 1;
    for (int k = threadIdx.x; k < N; k += SELT) {
        if (k < n) { ss[k] = cd[k].s; si[k] = cd[k].i; }
        else       { ss[k] = -INFINITY; si[k] = 0x40000000 + k; }
    }
    __syncthreads();
    bitonicShared(ss, si, N);   // uses blockDim.x internally

    const float* locp; const float* boxp; int HW;
    switch (li) {
        case 0: locp = l0; boxp = b0; HW = HW0; break;
        case 1: locp = l1; boxp = b1; HW = HW1; break;
        case 2: locp = l2; boxp = b2; HW = HW2; break;
        case 3: locp = l3; boxp = b3; HW = HW3; break;
        default: locp = l4; boxp = b4; HW = HW4; break;
    }
    for (int j = threadIdx.x; j < TOPN; j += SELT) {
        int cidx = b * KC + li * TOPN + j;
        bool ok = (j < n);
        float s = ok ? ss[j] : -INFINITY;
        ok = ok && (s > 0.0f);
        if (ok) {
            int idx = si[j];
            int hw = idx / NC, c = idx - hw * NC;
            float lx = locp[hw * 2 + 0], ly = locp[hw * 2 + 1];
            const float* bp = boxp + (size_t)b * 4 * HW + hw;
            float bl = bp[0], bt = bp[HW], br = bp[2 * HW], bb = bp[3 * HW];
            float x1 = fminf(fmaxf(__fsub_rn(lx, bl), 0.0f), 1023.0f);
            float y1 = fminf(fmaxf(__fsub_rn(ly, bt), 0.0f),  799.0f);
            float x2 = fminf(fmaxf(__fadd_rn(lx, br), 0.0f), 1023.0f);
            float y2 = fminf(fmaxf(__fadd_rn(ly, bb), 0.0f),  799.0f);
            cbox[cidx * 4 + 0] = x1; cbox[cidx * 4 + 1] = y1;
            cbox[cidx * 4 + 2] = x2; cbox[cidx * 4 + 3] = y2;
            csc[cidx] = sqrtf(fmaxf(s, 1e-12f));
            clb[cidx] = c + 1;
        } else {
            cbox[cidx * 4 + 0] = 0.0f; cbox[cidx * 4 + 1] = 0.0f;
            cbox[cidx * 4 + 2] = 0.0f; cbox[cidx * 4 + 3] = 0.0f;
            csc[cidx] = -INFINITY;
            clb[cidx] = 0;
        }
    }
}

// ---------------- K4: 5-way merge by rank (stable, matches argsort(-s) exactly) -----
__global__ __launch_bounds__(THREADS) void k_merge(
        const float* __restrict__ csc, const int* __restrict__ clb, const float* __restrict__ cbox,
        float* __restrict__ ssc, int* __restrict__ slb, float* __restrict__ sbox,
        float* __restrict__ obox) {
    int li = blockIdx.x, b = blockIdx.y;
    __shared__ float ss[KC];
    for (int k = threadIdx.x; k < KC; k += THREADS) ss[k] = csc[b * KC + k];
    __syncthreads();
    for (int j = threadIdx.x; j < TOPN; j += THREADS) {
        int k = li * TOPN + j;
        float s = ss[k];
        int rank = j;
        #pragma unroll
        for (int l = 0; l < NLEV; ++l) {
            if (l == li) continue;                 // wave-uniform branch
            const float* seg = ss + l * TOPN;
            int lo = 0, hi = TOPN;
            if (l < li) {
                while (lo < hi) { int m = (lo + hi) >> 1; if (seg[m] >= s) lo = m + 1; else hi = m; }
            } else {
                while (lo < hi) { int m = (lo + hi) >> 1; if (seg[m] >  s) lo = m + 1; else hi = m; }
            }
            rank += lo;
        }
        int src = b * KC + k, dst = b * KC + rank;
        int lab = clb[src];
        ssc[dst] = s; slb[dst] = lab;
        float off = __fmul_rn((float)lab, 1025.0f);   // offset = max(800,1024)+1
        float4 v = *(const float4*)&cbox[(size_t)src * 4];
        *(float4*)&sbox[(size_t)dst * 4] = v;
        float4 o;
        o.x = __fadd_rn(v.x, off); o.y = __fadd_rn(v.y, off);
        o.z = __fadd_rn(v.z, off); o.w = __fadd_rn(v.w, off);
        *(float4*)&obox[(size_t)dst * 4] = o;
    }
}

// ---------------- K5: suppression bitmask (iou > 0.6 && j > i), triangular grid -----
__global__ __launch_bounds__(64) void k_iou(const float* __restrict__ obox,
                                            unsigned long long* __restrict__ MT) {
    // decode lower-triangle pair index -> (tile, w) with w >= tile
    int t = blockIdx.x, b = blockIdx.y;
    int tile = 0, rem = t;
    while (rem >= WORDS - tile) { rem -= WORDS - tile; ++tile; }
    int w = tile + rem;
    int lane = threadIdx.x;
    __shared__ float4 sj[64];
    __shared__ float aj[64];
    const float4* op = (const float4*)obox + (size_t)b * KC;
    int j0 = w * 64;
    int jl = j0 + lane;
    float4 vj = op[(jl < KC) ? jl : (KC - 1)];
    sj[lane] = vj;
    aj[lane] = __fmul_rn(__fsub_rn(vj.z, vj.x), __fsub_rn(vj.w, vj.y));
    int i = tile * 64 + lane;
    float4 bi = op[(i < KC) ? i : (KC - 1)];
    float ai = __fmul_rn(__fsub_rn(bi.z, bi.x), __fsub_rn(bi.w, bi.y));
    __syncthreads();
    unsigned long long bits = 0;
    int jmax = min(64, KC - j0);
    for (int jj = 0; jj < jmax; ++jj) {
        float4 bj = sj[jj];            // wave-uniform -> LDS broadcast
        float xx1 = fmaxf(bi.x, bj.x), yy1 = fmaxf(bi.y, bj.y);
        float xx2 = fminf(bi.z, bj.z), yy2 = fminf(bi.w, bj.w);
        float ww = fmaxf(__fsub_rn(xx2, xx1), 0.0f);
        float hh = fmaxf(__fsub_rn(yy2, yy1), 0.0f);
        float inter = __fmul_rn(ww, hh);
        float uni = __fsub_rn(__fadd_rn(ai, aj[jj]), inter);
        float iou = __fdiv_rn(inter, fmaxf(uni, 1e-9f));
        bool kp = ((j0 + jj) > i) && (iou > 0.6f);
        bits |= kp ? (1ull << jj) : 0ull;
    }
    if (i >= KC) bits = 0;
    MT[((size_t)b * WORDS + w) * KROWS + i] = bits;
}

// ---------------- K6: pipelined pull-style greedy scan, early-exit at POSTN kept ------
__global__ __launch_bounds__(64) void k_nms(
        const unsigned long long* __restrict__ MT, const float* __restrict__ ssc,
        const int* __restrict__ slb, const float* __restrict__ sbox, float* __restrict__ out) {
    int b = blockIdx.x, lane = threadIdx.x;
    for (int k = lane; k < POSTN * 5; k += 64) out[(size_t)b * POSTN * 5 + k] = 0.0f;
    for (int k = lane; k < POSTN; k += 64) {
        out[(size_t)NB * POSTN * 5 + b * POSTN + k] = 0.0f;                 // labels
        out[(size_t)NB * POSTN * 5 + NB * POSTN + b * POSTN + k] = 0.0f;    // valid
    }
    const float* sp = ssc + b * KC;
    unsigned long long validV = 0;
    for (int c = 0; c < WORDS; ++c) {
        int i = c * 64 + lane;
        bool f = (i < KC) && (sp[i] > 0.0f);
        unsigned long long m = __ballot(f);
        validV = (lane == c) ? m : validV;
    }
    unsigned long long mybit = 1ull << lane;
    unsigned long long keptV = 0;
    const unsigned long long* Mb = MT + (size_t)b * WORDS * KROWS;

    unsigned long long pv[WORDS];
    pv[0] = Mb[lane];

    int keptTotal = 0;
    for (int t = 0; t < WORDS; ++t) {
        int tn = (t + 1 < WORDS) ? (t + 1) : t;
        const unsigned long long* cp = Mb + (size_t)tn * KROWS + lane;
        unsigned long long nv[WORDS];
        #pragma unroll
        for (int c = 0; c < WORDS; ++c) {
            int cc = (c <= tn) ? c : 0;
            nv[c] = cp[(size_t)cc * 64];
        }
        __builtin_amdgcn_sched_barrier(0);    // loads stay above; compute below

        unsigned long long D = pv[t];
        unsigned long long acc = 0;
        #pragma unroll
        for (int c = 0; c < WORDS; ++c) {
            if (c < t) {
                unsigned long long kc = readlane64(keptV, c);
                if (kc & mybit) acc |= pv[c];
            }
        }
        #pragma unroll
        for (int s = 1; s < 64; s <<= 1) acc |= __shfl_xor(acc, s, 64);

        unsigned long long validT = readlane64(validV, t);
        unsigned long long rem = acc;
        unsigned long long sup = __ballot(D != 0ull) & validT;
        unsigned long long todoS = sup;
        while (todoS) {
            int r = __builtin_ctzll(todoS);
            todoS &= todoS - 1;
            if (!((rem >> r) & 1ull)) {
                unsigned long long Dr = readlane64(D, r);
                rem |= Dr;
                todoS &= ~Dr;
            }
        }
        unsigned long long kept = validT & ~rem;
        keptV = (lane == t) ? kept : keptV;

        keptTotal += (int)__popcll(kept);      // kept is wave-uniform
        if (keptTotal >= POSTN) break;         // first POSTN kept fully determined

        #pragma unroll
        for (int c = 0; c < WORDS; ++c) pv[c] = nv[c];
    }

    int base = 0;
    for (int c = 0; c < WORDS && base < POSTN; ++c) {
        unsigned long long kw = readlane64(keptV, c);
        bool f = (kw & mybit) != 0ull;
        int rank = base + __popcll(kw & (mybit - 1ull));
        if (f && rank < POSTN) {
            int i = c * 64 + lane;
            int src = b * KC + i;
            float* o5 = out + ((size_t)b * POSTN + rank) * 5;
            o5[0] = sbox[src * 4 + 0]; o5[1] = sbox[src * 4 + 1];
            o5[2] = sbox[src * 4 + 2]; o5[3] = sbox[src * 4 + 3];
            o5[4] = ssc[src];
            out[(size_t)NB * POSTN * 5 + b * POSTN + rank] = (float)slb[src];
            out[(size_t)NB * POSTN * 5 + NB * POSTN + b * POSTN + rank] = 1.0f;
        }
        base += __popcll(kw);
    }
}

// ---------------- launch (7 dispatches — the proven round-5 structure) ----------------
extern "C" void kernel_launch(void* const* d_in, const int* in_sizes, int n_in,
                              void* d_out, int out_size, void* d_ws, size_t ws_size,
                              hipStream_t stream) {
    const float *loc[5], *cls[5], *box[5], *ctr[5];
    for (int l = 0; l < 5; ++l) {
        loc[l] = (const float*)d_in[l * 4 + 0];
        cls[l] = (const float*)d_in[l * 4 + 1];
        box[l] = (const float*)d_in[l * 4 + 2];
        ctr[l] = (const float*)d_in[l * 4 + 3];
    }
    char* ws = (char*)d_ws;
    unsigned* hist = (unsigned*)(ws + OFF_HIST);
    unsigned* cnt  = (unsigned*)(ws + OFF_CNT);
    Cand* cand     = (Cand*)(ws + OFF_CAND);
    float* cbox    = (float*)(ws + OFF_CBOX);
    float* csc     = (float*)(ws + OFF_CSC);
    int*   clb     = (int*)(ws + OFF_CLB);
    float* ssc     = (float*)(ws + OFF_SSC);
    int*   slb     = (int*)(ws + OFF_SLB);
    float* sbox    = (float*)(ws + OFF_SBOX);
    float* obox    = (float*)(ws + OFF_OBOX);
    unsigned long long* MT = (unsigned long long*)(ws + OFF_M);
    unsigned short* gmx = (unsigned short*)(ws + OFF_GMX);
    float* out = (float*)d_out;

    int zn = (int)(OFF_CAND / 4);
    k_zero<<<(zn + THREADS - 1) / THREADS, THREADS, 0, stream>>>((unsigned*)ws, zn);
    k_hist<<<dim3(CHUNKS, NB), THREADS, 0, stream>>>(
        cls[0], cls[1], cls[2], cls[3], cls[4],
        ctr[0], ctr[1], ctr[2], ctr[3], ctr[4], gmx, hist);
    k_collect<<<dim3(BPP, NPAIR), THREADS, 0, stream>>>(
        cls[0], cls[1], cls[2], cls[3], cls[4],
        ctr[0], ctr[1], ctr[2], ctr[3], ctr[4], hist, gmx, cand, cnt);
    k_select<<<NPAIR, SELT, 0, stream>>>(
        cand, cnt,
        loc[0], loc[1], loc[2], loc[3], loc[4],
        box[0], box[1], box[2], box[3], box[4],
        cbox, csc, clb);
    k_merge<<<dim3(NLEV, NB), THREADS, 0, stream>>>(csc, clb, cbox, ssc, slb, sbox, obox);
    k_iou<<<dim3(NTRI, NB), 64, 0, stream>>>(obox, MT);
    k_nms<<<NB, 64, 0, stream>>>(MT, ssc, slb, sbox, out);
}